// Round 7
// baseline (100.996 us; speedup 1.0000x reference)
//
#include <hip/hip_runtime.h>
#include <hip/hip_bf16.h>

#define Bsz 256
#define Tn 2048
#define QD 1024
#define AD 128
#define DCn 8
#define DKn 21
#define PLn 11
#define GN (DCn * DKn)   // 168
#define MS 32            // M16 row stride in halfs (64 B rows, 16B-aligned frags)

typedef _Float16 f16x8 __attribute__((ext_vector_type(8)));
typedef float f32x4 __attribute__((ext_vector_type(4)));
typedef unsigned int u32;

#define TWO_LOG2E 2.8853900817779268f   // 2*log2(e): folds tanh's 2x and exp->exp2

// RNE pack of two floats into a (f16,f16) dword — matches (_Float16) cast rounding.
__device__ __forceinline__ u32 pkh_rne(float a, float b) {
    union { _Float16 h[2]; u32 u; } p;
    p.h[0] = (_Float16)a; p.h[1] = (_Float16)b;
    return p.u;
}

// ---------------------------------------------------------------------------
// Algebraic fusion: z[t][a] = sum_k win[t][k]*M[a][k] + b[a], with
//   M = U_w . F  +  T_w . G_b   (128 x 21, per batch).
// R7 = R4 base (known-good) + two minimal latency edits:
//   g1 tail: lane i captures row i's butterfly sum (1 cndmask/row, sums
//            bitwise identical to R4); the 8 tanhf run concurrently on
//            lanes 0-7 instead of serially on lane 0.
//   g2:      V_w float4 loads prefetched into registers before barrier-1
//            (cold-miss latency hides under g1's L2 stream); post-barrier
//            g2 is pure register fma.
// ---------------------------------------------------------------------------
__global__ __launch_bounds__(1024, 4) void dca_kernel(
    const float* __restrict__ query, const float* __restrict__ align,
    const float* __restrict__ P, const float* __restrict__ W_w,
    const float* __restrict__ W_b, const float* __restrict__ V_w,
    const float* __restrict__ F_w, const float* __restrict__ U_w,
    const float* __restrict__ T_w, const float* __restrict__ T_b,
    const float* __restrict__ v_w, float* __restrict__ out)
{
    __shared__ __align__(16) _Float16 al16[Tn + 44];
    __shared__ float    pcb[Tn];
    __shared__ float    sden[Tn];
    __shared__ __align__(16) float h_lds[AD];
    __shared__ float    G_lds[GN];
    __shared__ __align__(16) _Float16 M16[AD * MS];   // 8 KB fused weights
    __shared__ float    red[16];
    __shared__ float    bc;

    const int b    = blockIdx.x;
    const int tid  = threadIdx.x;
    const int lane = tid & 63;
    const int wid  = tid >> 6;
    const int l15  = lane & 15;
    const int quad = lane >> 4;

    // ---- P0: stage alignment row as f16 (pad=10 each side; i ~ t=i-10) ----
    if (tid < 512) {
        float4 v = ((const float4*)(align + (size_t)b * Tn))[tid];
        u32* dst = (u32*)&al16[10 + tid * 4];
        dst[0] = pkh_rne(v.x, v.y);
        dst[1] = pkh_rne(v.z, v.w);
    } else if (tid < 576) {
        int k = tid - 512;
        if (k < 10)       al16[k]      = (_Float16)0.f;
        else if (k < 44)  al16[Tn + k] = (_Float16)0.f;
    }

    // ---- P0: g1: h = tanh(W_w q + W_b); wave handles 8 a-rows ----
    {
        const float4* q4 = (const float4*)(query + (size_t)b * QD);
        float4 q0 = q4[lane];
        float4 q1 = q4[64 + lane];
        float4 q2 = q4[128 + lane];
        float4 q3 = q4[192 + lane];

        float myu = 0.f;                     // row (lane)'s sum, lanes 0-7
        #pragma unroll 2
        for (int i = 0; i < 8; ++i) {
            int a = wid * 8 + i;
            const float4* w4 = (const float4*)(W_w + (size_t)a * QD);
            float4 x0 = w4[lane];
            float4 x1 = w4[64 + lane];
            float4 x2 = w4[128 + lane];
            float4 x3 = w4[192 + lane];
            float accA = 0.f, accB = 0.f;
            accA = fmaf(q0.x, x0.x, fmaf(q0.y, x0.y, fmaf(q0.z, x0.z, fmaf(q0.w, x0.w, accA))));
            accB = fmaf(q1.x, x1.x, fmaf(q1.y, x1.y, fmaf(q1.z, x1.z, fmaf(q1.w, x1.w, accB))));
            accA = fmaf(q2.x, x2.x, fmaf(q2.y, x2.y, fmaf(q2.z, x2.z, fmaf(q2.w, x2.w, accA))));
            accB = fmaf(q3.x, x3.x, fmaf(q3.y, x3.y, fmaf(q3.z, x3.z, fmaf(q3.w, x3.w, accB))));
            float acc = accA + accB;
            #pragma unroll
            for (int off = 32; off; off >>= 1) acc += __shfl_xor(acc, off);
            myu = (lane == i) ? acc : myu;   // capture row i's sum on lane i
        }

        // V_w register prefetch for g2 (no h dependency): issue before the
        // barrier so the (cold) L2/HBM latency hides under g1's tail.
        float4 vw0 = {0,0,0,0}, vw1 = {0,0,0,0}, vw2 = {0,0,0,0}, vw3 = {0,0,0,0};
        float4 vw4 = {0,0,0,0}, vw5 = {0,0,0,0}, vw6 = {0,0,0,0}, vw7 = {0,0,0,0};
        const int gr = tid >> 2, gs = tid & 3;
        if (tid < 4 * GN) {
            const float4* v4 = (const float4*)(V_w + (size_t)gr * AD + gs * 32);
            vw0 = v4[0]; vw1 = v4[1]; vw2 = v4[2]; vw3 = v4[3];
            vw4 = v4[4]; vw5 = v4[5]; vw6 = v4[6]; vw7 = v4[7];
        }

        if (lane < 8) {                      // 8 concurrent tanh evaluations
            int a = wid * 8 + lane;
            h_lds[a] = tanhf(myu + W_b[a]);
        }

        __syncthreads();   // b1: h_lds + al16 ready (reached by all threads)

        // ---- P1: g2 (4-way split): G[r] = V_w[r] . h, from prefetched regs ----
        if (tid < 4 * GN) {
            const float4* h4 = (const float4*)(h_lds + gs * 32);
            float g = 0.f;
            float4 hh;
            hh = h4[0]; g = fmaf(vw0.x, hh.x, fmaf(vw0.y, hh.y, fmaf(vw0.z, hh.z, fmaf(vw0.w, hh.w, g))));
            hh = h4[1]; g = fmaf(vw1.x, hh.x, fmaf(vw1.y, hh.y, fmaf(vw1.z, hh.z, fmaf(vw1.w, hh.w, g))));
            hh = h4[2]; g = fmaf(vw2.x, hh.x, fmaf(vw2.y, hh.y, fmaf(vw2.z, hh.z, fmaf(vw2.w, hh.w, g))));
            hh = h4[3]; g = fmaf(vw3.x, hh.x, fmaf(vw3.y, hh.y, fmaf(vw3.z, hh.z, fmaf(vw3.w, hh.w, g))));
            hh = h4[4]; g = fmaf(vw4.x, hh.x, fmaf(vw4.y, hh.y, fmaf(vw4.z, hh.z, fmaf(vw4.w, hh.w, g))));
            hh = h4[5]; g = fmaf(vw5.x, hh.x, fmaf(vw5.y, hh.y, fmaf(vw5.z, hh.z, fmaf(vw5.w, hh.w, g))));
            hh = h4[6]; g = fmaf(vw6.x, hh.x, fmaf(vw6.y, hh.y, fmaf(vw6.z, hh.z, fmaf(vw6.w, hh.w, g))));
            hh = h4[7]; g = fmaf(vw7.x, hh.x, fmaf(vw7.y, hh.y, fmaf(vw7.z, hh.z, fmaf(vw7.w, hh.w, g))));
            g += __shfl_xor(g, 1);
            g += __shfl_xor(g, 2);
            if (gs == 0) G_lds[gr] = g;
        }
    }

    // ---- P1: prior, wave-local ----
    const int t0w = wid * 128;
    #pragma unroll
    for (int tt = 0; tt < 2; ++tt) {
        int t = t0w + tt * 64 + lane;
        float pr = 0.f;
        #pragma unroll
        for (int k = 0; k < PLn; ++k) pr = fmaf((float)al16[t + k], P[k], pr);
        pcb[t] = fmaxf(pr, 1e-6f);
    }

    // ---- P1: in-lane v-weights: vnq[n][r] = -2*v_w[n*16 + quad*4 + r] ----
    f32x4 vnq[8];
    float vsum = 0.f;
    #pragma unroll
    for (int n = 0; n < 8; ++n) {
        f32x4 vq = *(const f32x4*)(v_w + n * 16 + quad * 4);
        vsum += vq[0] + vq[1] + vq[2] + vq[3];
        vq[0] *= -2.f; vq[1] *= -2.f; vq[2] *= -2.f; vq[3] *= -2.f;
        vnq[n] = vq;
    }
    vsum += __shfl_xor(vsum, 16);
    vsum += __shfl_xor(vsum, 32);   // full sum over 128 a's

    // ---- P1: M-build fragments with no G dependency ----
    // Wave w: atile = w&7 (a-rows atile*16..+15), ktile = w>>3 (k-cols ktile*16..+15)
    const int atile = wid & 7;
    const int ktile = wid >> 3;
    const int kcol  = ktile * 16 + l15;          // 0..31

    // A-frag: A[m=a_loc=l15][c=quad*8+j]: c<8 -> U row, 8..15 -> T row, else 0
    f16x8 Am = {};
    if (quad < 2) {
        const int a = atile * 16 + l15;
        const float* src = (quad == 0) ? (U_w + a * 8) : (T_w + a * 8);
        float4 lo = ((const float4*)src)[0];
        float4 hi = ((const float4*)src)[1];
        Am[0] = (_Float16)lo.x; Am[1] = (_Float16)lo.y;
        Am[2] = (_Float16)lo.z; Am[3] = (_Float16)lo.w;
        Am[4] = (_Float16)hi.x; Am[5] = (_Float16)hi.y;
        Am[6] = (_Float16)hi.z; Am[7] = (_Float16)hi.w;
    }
    // B-frag: B[c=quad*8+j][n=kcol]: quad0 = F[c][kcol] (global, G-independent)
    f16x8 Bm = {};
    if (quad == 0 && kcol < DKn) {
        #pragma unroll
        for (int j = 0; j < 8; ++j) Bm[j] = (_Float16)F_w[j * DKn + kcol];
    }

    __syncthreads();   // b2: G_lds ready

    // ---- P2: finish B-frag (G part) and build M16 ----
    if (quad == 1 && kcol < DKn) {
        #pragma unroll
        for (int j = 0; j < 8; ++j) Bm[j] = (_Float16)G_lds[j * DKn + kcol];
    }
    {
        f32x4 z = {};
        f32x4 Dm = __builtin_amdgcn_mfma_f32_16x16x32_f16(Am, Bm, z, 0, 0, 0);
        // D[m=a_loc=quad*4+r][n=kcol]; cols kcol>=21 are 0 (B cols zeroed).
        #pragma unroll
        for (int r = 0; r < 4; ++r) {
            int a = atile * 16 + quad * 4 + r;
            float val = TWO_LOG2E * Dm[r];
            if (ktile == 1 && l15 == 5) val = TWO_LOG2E * T_b[a];  // k=21 bias col
            M16[a * MS + kcol] = (_Float16)val;
        }
    }
    __syncthreads();   // b3: M16 ready

    // ---- P3: fused weight frags Mf[n]: A[m=a_loc=l15][k=quad*8+j] ----
    f16x8 Mf[8];
    #pragma unroll
    for (int n = 0; n < 8; ++n)
        Mf[n] = *(const f16x8*)&M16[(n * 16 + l15) * MS + quad * 8];

    // ---- main loop: 4 iterations of 2 tiles (32 t), all MFMAs independent ----
    float wsum = 0.f;

    #pragma unroll 1
    for (int m = 0; m < 8; m += 2) {
        const int ta  = t0w + m * 16;
        const int tb_ = ta + 16;

        // al-frags (MFMA *B* operand): B[k=tap=quad*8+j][n=t_loc=l15]
        f16x8 Ac0, Ac1;
        #pragma unroll
        for (int j = 0; j < 8; ++j) {
            Ac0[j] = al16[ta  + l15 + quad * 8 + j];
            Ac1[j] = al16[tb_ + l15 + quad * 8 + j];
        }
        if (quad == 2) {            // k=21 bias channel rides a 1.0 input
            Ac0[5] = (_Float16)1.f;
            Ac1[5] = (_Float16)1.f;
        }

        float es0 = 0.f, es1 = 0.f;
        #pragma unroll
        for (int n = 0; n < 8; ++n) {
            f32x4 z2 = {};
            // d = 2*log2(e) * z ; D[m=a_loc=quad*4+r][n=t=l15]
            f32x4 d0 = __builtin_amdgcn_mfma_f32_16x16x32_f16(Mf[n], Ac0, z2, 0, 0, 0);
            f32x4 d1 = __builtin_amdgcn_mfma_f32_16x16x32_f16(Mf[n], Ac1, z2, 0, 0, 0);
            #pragma unroll
            for (int r = 0; r < 4; ++r) {
                float qa = __builtin_amdgcn_exp2f(d0[r]);
                float qb = __builtin_amdgcn_exp2f(d1[r]);
                float ra = __builtin_amdgcn_rcpf(qa + 1.f);
                float rb = __builtin_amdgcn_rcpf(qb + 1.f);
                es0 = fmaf(vnq[n][r], ra, es0);
                es1 = fmaf(vnq[n][r], rb, es1);
            }
        }
        // a-reduction across quads (t = l15 is the lane col)
        es0 += __shfl_xor(es0, 16);
        es0 += __shfl_xor(es0, 32);
        es1 += __shfl_xor(es1, 16);
        es1 += __shfl_xor(es1, 32);

        // epilogue on 32 lanes: tile A -> lanes 0-15, tile B -> lanes 16-31
        if (lane < 32) {
            int t    = ((lane < 16) ? ta : tb_) + l15;
            float e  = (lane < 16) ? es0 : es1;
            float sv = pcb[t] * __expf(e + vsum);
            sden[t] = sv;
            wsum += sv;
        }
    }

    // ---- P4: block sum + normalize ----
    __syncthreads();
    #pragma unroll
    for (int off = 32; off; off >>= 1) wsum += __shfl_xor(wsum, off);
    if (lane == 0) red[wid] = wsum;
    __syncthreads();
    if (wid == 0) {
        float ss = (lane < 16) ? red[lane] : 0.f;
        #pragma unroll
        for (int off = 8; off; off >>= 1) ss += __shfl_xor(ss, off);
        if (lane == 0) bc = ss;
    }
    __syncthreads();
    const float inv = 1.f / bc;
    out[b * Tn + tid]        = sden[tid] * inv;
    out[b * Tn + tid + 1024] = sden[tid + 1024] * inv;
}

// ---------------------------------------------------------------------------
extern "C" void kernel_launch(void* const* d_in, const int* in_sizes, int n_in,
                              void* d_out, int out_size, void* d_ws, size_t ws_size,
                              hipStream_t stream) {
    const float* query = (const float*)d_in[0];
    const float* align = (const float*)d_in[1];
    const float* P     = (const float*)d_in[2];
    const float* W_w   = (const float*)d_in[3];
    const float* W_b   = (const float*)d_in[4];
    const float* V_w   = (const float*)d_in[5];
    const float* F_w   = (const float*)d_in[6];
    const float* U_w   = (const float*)d_in[7];
    const float* T_w   = (const float*)d_in[8];
    const float* T_b   = (const float*)d_in[9];
    const float* v_w   = (const float*)d_in[10];
    float* out = (float*)d_out;

    dca_kernel<<<Bsz, 1024, 0, stream>>>(query, align, P, W_w, W_b, V_w,
                                         F_w, U_w, T_w, T_b, v_w, out);
}